// Round 4
// baseline (6081.637 us; speedup 1.0000x reference)
//
#include <hip/hip_runtime.h>
#include <hip/hip_bf16.h>
#include <cstddef>

// DeepSeekBlock: B=2 T=1024 D=2048 H=16 NOPE=128 ROPE=64 QKD=192
// QLORA=1536 KVLORA=512 VHD=128 INTER=8192
// Round 4: inputs f32 (runtime-detected, confirmed), OUTPUT F32 (the round-3 bug:
// reference returns jnp.float32; "bf16" in harness label is hard-coded text).
// f32 compute; per-batch arena: 56.25 MiB + 256 B.
// SOFTSCALE = QKD * -0.5 = -96.0 (sic). Precise 1/sqrtf in rmsnorm (score path
// is multiplied by -96; approximate rsqrt jitter would perturb softmax rows).

#define TT 1024
#define DD 2048

using bf16 = __hip_bfloat16;

__device__ __forceinline__ float us2f(unsigned short u) {
    return __uint_as_float(((unsigned int)u) << 16);
}

__device__ __forceinline__ float ldf(const void* p, size_t i, int isbf) {
    return isbf ? us2f(((const unsigned short*)p)[i]) : ((const float*)p)[i];
}

// ---------------- input dtype detection (kept: zero-cost, robust) ----------------
__global__ __launch_bounds__(64) void detect_k(const void* __restrict__ x,
                                               int* __restrict__ flag)
{
    __shared__ int cnt;
    if (threadIdx.x == 0) cnt = 0;
    __syncthreads();
    const unsigned short* u = (const unsigned short*)x;
    int bad = 0;
    for (int i = threadIdx.x; i < 512; i += 64) {
        const float v = us2f(u[i]);
        const float a = fabsf(v);
        if (!(a < 1e6f) || (v != 0.0f && a < 1e-30f)) bad++;
    }
    atomicAdd(&cnt, bad);
    __syncthreads();
    if (threadIdx.x == 0) *flag = (cnt > 32) ? 0 : 1;   // 0 = f32, 1 = bf16
}

// ---------------- rmsnorm over f32 rows (w dual-dtype) ----------------
__global__ __launch_bounds__(256) void rmsnorm_k(
    const float* __restrict__ in, const void* __restrict__ w,
    float* __restrict__ out, int L, int istride, int ostride,
    const int* __restrict__ flag)
{
    const int isbf = *flag;
    const int m = blockIdx.x, tid = threadIdx.x;
    const float* row = in + (size_t)m * istride;
    float ss = 0.f;
    for (int i = tid; i < L; i += 256) { float v = row[i]; ss += v * v; }
    __shared__ float red[256];
    red[tid] = ss; __syncthreads();
    for (int s = 128; s > 0; s >>= 1) {
        if (tid < s) red[tid] += red[tid + s];
        __syncthreads();
    }
    const float scale = 1.0f / sqrtf(red[0] / (float)L + 1e-6f);
    float* orow = out + (size_t)m * ostride;
    for (int i = tid; i < L; i += 256)
        orow[i] = row[i] * scale * ldf(w, i, isbf);
}

// rmsnorm on input x (dual, element offset eoff); writes f32 copy of x too
__global__ __launch_bounds__(256) void rmsnorm_x_k(
    const void* __restrict__ x, size_t eoff, const void* __restrict__ w,
    float* __restrict__ h, float* __restrict__ xf,
    const int* __restrict__ flag)
{
    const int isbf = *flag;
    const int m = blockIdx.x, tid = threadIdx.x;
    const size_t base = eoff + (size_t)m * DD;
    float* xrow = xf + (size_t)m * DD;
    float ss = 0.f;
    float vals[8];
    for (int i = 0; i < 8; ++i) {
        float v = ldf(x, base + tid + 256 * i, isbf);
        vals[i] = v; ss += v * v;
        xrow[tid + 256 * i] = v;
    }
    __shared__ float red[256];
    red[tid] = ss; __syncthreads();
    for (int s = 128; s > 0; s >>= 1) {
        if (tid < s) red[tid] += red[tid + s];
        __syncthreads();
    }
    const float scale = 1.0f / sqrtf(red[0] / (float)DD + 1e-6f);
    float* hrow = h + (size_t)m * DD;
    for (int i = 0; i < 8; ++i)
        hrow[tid + 256 * i] = vals[i] * scale * ldf(w, tid + 256 * i, isbf);
}

// ---------------- tiled f32 GEMM: C(M,N) = A(M,K) @ W(N,K)^T ----------------
// A f32 (ws); W dual-dtype input. EPI:
//  0: f32 out = acc
//  1: f32 out = R + acc         (R may alias outp; data-dep protects order)
//  3: f32 out = silu(R) * acc   (R aliases outp; fused SwiGLU)
template <int EPI>
__global__ __launch_bounds__(256, 2) void gemm_k(
    const float* __restrict__ A, const void* __restrict__ Wv,
    const float* __restrict__ R, float* __restrict__ C,
    int N, int K, const int* __restrict__ flag)
{
    const int isbf = *flag;
    __shared__ __align__(16) float As[16][68];
    __shared__ __align__(16) float Ws[16][68];
    const int tid = threadIdx.x;
    const int tx = tid & 15, ty = tid >> 4;
    const int bn = blockIdx.x << 6, bm = blockIdx.y << 6;
    const int lr = tid >> 2;
    const int lk = (tid & 3) << 2;
    const float* Ald = A + (size_t)(bm + lr) * K + lk;
    const size_t wbase = (size_t)(bn + lr) * K + lk;

    float acc[4][4] = {};
    for (int kt = 0; kt < K; kt += 16) {
        float4 av = *(const float4*)(Ald + kt);
        float w0, w1, w2, w3;
        if (isbf) {
            ushort4 wv = *(const ushort4*)((const unsigned short*)Wv + wbase + kt);
            w0 = us2f(wv.x); w1 = us2f(wv.y); w2 = us2f(wv.z); w3 = us2f(wv.w);
        } else {
            float4 wv = *(const float4*)((const float*)Wv + wbase + kt);
            w0 = wv.x; w1 = wv.y; w2 = wv.z; w3 = wv.w;
        }
        __syncthreads();
        As[lk + 0][lr] = av.x; As[lk + 1][lr] = av.y;
        As[lk + 2][lr] = av.z; As[lk + 3][lr] = av.w;
        Ws[lk + 0][lr] = w0; Ws[lk + 1][lr] = w1;
        Ws[lk + 2][lr] = w2; Ws[lk + 3][lr] = w3;
        __syncthreads();
#pragma unroll
        for (int kk = 0; kk < 16; ++kk) {
            float4 a4 = *(const float4*)&As[kk][ty << 2];
            float4 w4 = *(const float4*)&Ws[kk][tx << 2];
            float a_[4] = {a4.x, a4.y, a4.z, a4.w};
            float w_[4] = {w4.x, w4.y, w4.z, w4.w};
#pragma unroll
            for (int i = 0; i < 4; ++i)
#pragma unroll
                for (int j = 0; j < 4; ++j)
                    acc[i][j] = fmaf(a_[i], w_[j], acc[i][j]);
        }
    }

    const int r0 = bm + (ty << 2), c0 = bn + (tx << 2);
    if (EPI == 0) {
#pragma unroll
        for (int i = 0; i < 4; ++i) {
            float4 v = {acc[i][0], acc[i][1], acc[i][2], acc[i][3]};
            *(float4*)&C[(size_t)(r0 + i) * N + c0] = v;
        }
    } else if (EPI == 1) {
#pragma unroll
        for (int i = 0; i < 4; ++i) {
            float4 rs = *(const float4*)&R[(size_t)(r0 + i) * N + c0];
            float4 v = {acc[i][0] + rs.x, acc[i][1] + rs.y,
                        acc[i][2] + rs.z, acc[i][3] + rs.w};
            *(float4*)&C[(size_t)(r0 + i) * N + c0] = v;
        }
    } else {  // EPI == 3: out = silu(R) * acc
#pragma unroll
        for (int i = 0; i < 4; ++i) {
            float4 g = *(const float4*)&R[(size_t)(r0 + i) * N + c0];
            float gv[4] = {g.x, g.y, g.z, g.w};
            float o[4];
#pragma unroll
            for (int j = 0; j < 4; ++j) {
                const float sg = 1.0f / (1.0f + __expf(-gv[j]));
                o[j] = gv[j] * sg * acc[i][j];
            }
            float4 v = {o[0], o[1], o[2], o[3]};
            *(float4*)&C[(size_t)(r0 + i) * N + c0] = v;
        }
    }
}

// ---------------- RoPE (interleaved pairs), in-place on q and k_pe ----------------
__global__ __launch_bounds__(256) void rope_k(
    float* __restrict__ qb, float* __restrict__ kva,
    const void* __restrict__ fc, const void* __restrict__ fs,
    const int* __restrict__ flag)
{
    const int isbf = *flag;
    const int t = blockIdx.x;
    const int tid = threadIdx.x;
    __shared__ float c[32], s[32];
    if (tid < 32) {
        c[tid] = ldf(fc, t * 32 + tid, isbf);
        s[tid] = ldf(fs, t * 32 + tid, isbf);
    }
    __syncthreads();
    for (int p = tid; p < 512; p += 256) {
        const int h = p >> 5, i = p & 31;
        float* base = qb + (size_t)t * 3072 + h * 192 + 128 + 2 * i;
        const float x0 = base[0], x1 = base[1];
        base[0] = x0 * c[i] - x1 * s[i];
        base[1] = x0 * s[i] + x1 * c[i];
    }
    if (tid < 32) {
        float* base = kva + (size_t)t * 576 + 512 + 2 * tid;
        const float x0 = base[0], x1 = base[1];
        base[0] = x0 * c[tid] - x1 * s[tid];
        base[1] = x0 * s[tid] + x1 * c[tid];
    }
}

// ---------------- causal attention, one block per (h,s), single batch ----------------
__global__ __launch_bounds__(256) void attn_k(
    const float* __restrict__ q, const float* __restrict__ kv,
    const float* __restrict__ kva, float* __restrict__ y)
{
    const int s = blockIdx.x, h = blockIdx.y;
    const int tid = threadIdx.x;
    __shared__ __align__(16) float qv[192];
    __shared__ float p[TT];
    __shared__ float red[256];

    const float* qrow = q + (size_t)s * 3072 + h * 192;
    if (tid < 192) qv[tid] = qrow[tid];
    __syncthreads();

    const float4* q4 = (const float4*)qv;
    float lmax = -1e30f;
    for (int t = tid; t <= s; t += 256) {
        const float4* k4 = (const float4*)(kv + (size_t)t * 4096 + h * 256);
        const float4* pe4 = (const float4*)(kva + (size_t)t * 576 + 512);
        float d = 0.f;
#pragma unroll 8
        for (int k = 0; k < 32; ++k) {
            float4 kk = k4[k], qq = q4[k];
            d += qq.x * kk.x + qq.y * kk.y + qq.z * kk.z + qq.w * kk.w;
        }
#pragma unroll 8
        for (int k = 0; k < 16; ++k) {
            float4 kk = pe4[k], qq = q4[32 + k];
            d += qq.x * kk.x + qq.y * kk.y + qq.z * kk.z + qq.w * kk.w;
        }
        const float sc = d * -96.0f;   // SOFTSCALE = QKD * -0.5
        p[t] = sc;
        lmax = fmaxf(lmax, sc);
    }
    red[tid] = lmax; __syncthreads();
    for (int w = 128; w > 0; w >>= 1) {
        if (tid < w) red[tid] = fmaxf(red[tid], red[tid + w]);
        __syncthreads();
    }
    const float mx = red[0];
    __syncthreads();

    float lsum = 0.f;
    for (int t = tid; t <= s; t += 256) {
        const float e = __expf(p[t] - mx);
        p[t] = e; lsum += e;
    }
    red[tid] = lsum; __syncthreads();
    for (int w = 128; w > 0; w >>= 1) {
        if (tid < w) red[tid] += red[tid + w];
        __syncthreads();
    }
    const float inv = 1.0f / red[0];

    if (tid < 128) {
        float acc = 0.f;
        const float* vbase = kv + h * 256 + 128 + tid;
        for (int t = 0; t <= s; ++t)
            acc += p[t] * vbase[(size_t)t * 4096];
        y[(size_t)s * 2048 + h * 128 + tid] = acc * inv;
    }
}

extern "C" void kernel_launch(void* const* d_in, const int* in_sizes, int n_in,
                              void* d_out, int out_size, void* d_ws, size_t ws_size,
                              hipStream_t stream) {
    (void)in_sizes; (void)n_in; (void)out_size; (void)ws_size;
    const void* x       = d_in[0];
    const void* fcos    = d_in[2];
    const void* fsin    = d_in[3];
    const void* attn_nw = d_in[4];
    const void* wq_a    = d_in[5];
    const void* q_nw    = d_in[6];
    const void* wq_b    = d_in[7];
    const void* wkv_a   = d_in[8];
    const void* kv_nw   = d_in[9];
    const void* wkv_b   = d_in[10];
    const void* wo      = d_in[11];
    const void* ffn_nw  = d_in[12];
    const void* w1      = d_in[13];
    const void* w2      = d_in[14];
    const void* w3      = d_in[15];

    int* flag = (int*)d_ws;
    float* a  = (float*)d_ws + 64;
    const size_t M1 = 1048576;
    float* xf  = a;                       // [0, 2M)  residual x -> x2 in place
    float* h   = a + 2 * M1;              // [2M, 4M) h, later h2
    float* qa  = a + 4 * M1;              // [4M, 5.5M) dead after qb GEMM
    float* yb  = a + 4 * M1;              // [4M, 6M)   attn out (qa dead)
    float* qb  = a + 6 * M1;              // [6M, 9M)
    float* kva = a + 9 * M1;              // 1024x576
    float* kvn = kva + 589824;            // 1024x512
    float* kvb = kvn + 524288;            // 1024x4096; arena ends at 14,745,600
    float* gb  = a + 4 * M1;              // [4M, 12M) FFN stage (all attn bufs dead)
    float* x2  = xf;
    float* h2  = h;

    detect_k<<<1, 64, 0, stream>>>(x, flag);

    for (int b = 0; b < 2; ++b) {
        const size_t eoff = (size_t)b * TT * DD;
        float* outb = (float*)d_out + eoff;   // reference output dtype: float32

        rmsnorm_x_k<<<TT, 256, 0, stream>>>(x, eoff, attn_nw, h, xf, flag);
        gemm_k<0><<<dim3(1536 / 64, TT / 64), 256, 0, stream>>>(h, wq_a, nullptr, qa, 1536, 2048, flag);
        rmsnorm_k<<<TT, 256, 0, stream>>>(qa, q_nw, qa, 1536, 1536, 1536, flag);
        gemm_k<0><<<dim3(3072 / 64, TT / 64), 256, 0, stream>>>(qa, wq_b, nullptr, qb, 3072, 1536, flag);
        gemm_k<0><<<dim3(576 / 64, TT / 64), 256, 0, stream>>>(h, wkv_a, nullptr, kva, 576, 2048, flag);
        rmsnorm_k<<<TT, 256, 0, stream>>>(kva, kv_nw, kvn, 512, 576, 512, flag);
        rope_k<<<TT, 256, 0, stream>>>(qb, kva, fcos, fsin, flag);
        gemm_k<0><<<dim3(4096 / 64, TT / 64), 256, 0, stream>>>(kvn, wkv_b, nullptr, kvb, 4096, 512, flag);
        attn_k<<<dim3(TT, 16), 256, 0, stream>>>(qb, kvb, kva, yb);
        gemm_k<1><<<dim3(2048 / 64, TT / 64), 256, 0, stream>>>(yb, wo, xf, x2, 2048, 2048, flag);
        rmsnorm_k<<<TT, 256, 0, stream>>>(x2, ffn_nw, h2, 2048, 2048, 2048, flag);
        gemm_k<0><<<dim3(8192 / 64, TT / 64), 256, 0, stream>>>(h2, w1, nullptr, gb, 8192, 2048, flag);
        gemm_k<3><<<dim3(8192 / 64, TT / 64), 256, 0, stream>>>(h2, w3, gb, gb, 8192, 2048, flag);
        gemm_k<1><<<dim3(2048 / 64, TT / 64), 256, 0, stream>>>(gb, w2, x2, outb, 2048, 8192, flag);
    }
}

// Round 5
// 3369.218 us; speedup vs baseline: 1.8051x; 1.8051x over previous
//
#include <hip/hip_runtime.h>
#include <hip/hip_bf16.h>
#include <cstddef>

// DeepSeekBlock: B=2 T=1024 D=2048 H=16 NOPE=128 ROPE=64 QKD=192
// QLORA=1536 KVLORA=512 VHD=128 INTER=8192
// Round 5: MFMA bf16 GEMMs for wo/w1/w3/w2 (223 of 269 GF); Q-tile=8 attention.
// Score path (wq_a/wq_b/wkv_a/wkv_b GEMMs, QK, softmax) stays f32: scores are
// scaled by SOFTSCALE=-96, so bf16-level score jitter flips near-tie softmax rows.
// Inputs f32 (runtime-detected flag kept), output f32. ws peak 56.0 MiB.

#define TT 1024
#define DD 2048
#define QT 8

using bf16 = __hip_bfloat16;
typedef __attribute__((ext_vector_type(8))) short short8;
typedef __attribute__((ext_vector_type(8))) unsigned short ushort8v;
typedef __attribute__((ext_vector_type(4))) float f32x4;

__device__ __forceinline__ float us2f(unsigned short u) {
    return __uint_as_float(((unsigned int)u) << 16);
}
__device__ __forceinline__ float ldf(const void* p, size_t i, int isbf) {
    return isbf ? us2f(((const unsigned short*)p)[i]) : ((const float*)p)[i];
}
__device__ __forceinline__ unsigned short f2bf(float f) {
    __hip_bfloat16 b = __float2bfloat16(f);
    return *reinterpret_cast<unsigned short*>(&b);
}

// ---------------- input dtype detection ----------------
__global__ __launch_bounds__(64) void detect_k(const void* __restrict__ x,
                                               int* __restrict__ flag)
{
    __shared__ int cnt;
    if (threadIdx.x == 0) cnt = 0;
    __syncthreads();
    const unsigned short* u = (const unsigned short*)x;
    int bad = 0;
    for (int i = threadIdx.x; i < 512; i += 64) {
        const float v = us2f(u[i]);
        const float a = fabsf(v);
        if (!(a < 1e6f) || (v != 0.0f && a < 1e-30f)) bad++;
    }
    atomicAdd(&cnt, bad);
    __syncthreads();
    if (threadIdx.x == 0) *flag = (cnt > 32) ? 0 : 1;   // 0 = f32, 1 = bf16
}

// ---------------- rmsnorm f32->f32 ----------------
__global__ __launch_bounds__(256) void rmsnorm_k(
    const float* __restrict__ in, const void* __restrict__ w,
    float* __restrict__ out, int L, int istride, int ostride,
    const int* __restrict__ flag)
{
    const int isbf = *flag;
    const int m = blockIdx.x, tid = threadIdx.x;
    const float* row = in + (size_t)m * istride;
    float ss = 0.f;
    for (int i = tid; i < L; i += 256) { float v = row[i]; ss += v * v; }
    __shared__ float red[256];
    red[tid] = ss; __syncthreads();
    for (int s = 128; s > 0; s >>= 1) {
        if (tid < s) red[tid] += red[tid + s];
        __syncthreads();
    }
    const float scale = 1.0f / sqrtf(red[0] / (float)L + 1e-6f);
    float* orow = out + (size_t)m * ostride;
    for (int i = tid; i < L; i += 256)
        orow[i] = row[i] * scale * ldf(w, i, isbf);
}

// ---------------- rmsnorm f32->bf16 (FFN input; feeds bf16 MFMA GEMMs) ----------------
__global__ __launch_bounds__(256) void rmsnorm_bf_k(
    const float* __restrict__ in, const void* __restrict__ w,
    unsigned short* __restrict__ out, int L,
    const int* __restrict__ flag)
{
    const int isbf = *flag;
    const int m = blockIdx.x, tid = threadIdx.x;
    const float* row = in + (size_t)m * L;
    float ss = 0.f;
    for (int i = tid; i < L; i += 256) { float v = row[i]; ss += v * v; }
    __shared__ float red[256];
    red[tid] = ss; __syncthreads();
    for (int s = 128; s > 0; s >>= 1) {
        if (tid < s) red[tid] += red[tid + s];
        __syncthreads();
    }
    const float scale = 1.0f / sqrtf(red[0] / (float)L + 1e-6f);
    unsigned short* orow = out + (size_t)m * L;
    for (int i = tid; i < L; i += 256)
        orow[i] = f2bf(row[i] * scale * ldf(w, i, isbf));
}

// rmsnorm on input x (dual, element offset); also writes f32 copy (residual)
__global__ __launch_bounds__(256) void rmsnorm_x_k(
    const void* __restrict__ x, size_t eoff, const void* __restrict__ w,
    float* __restrict__ h, float* __restrict__ xf,
    const int* __restrict__ flag)
{
    const int isbf = *flag;
    const int m = blockIdx.x, tid = threadIdx.x;
    const size_t base = eoff + (size_t)m * DD;
    float* xrow = xf + (size_t)m * DD;
    float ss = 0.f;
    float vals[8];
    for (int i = 0; i < 8; ++i) {
        float v = ldf(x, base + tid + 256 * i, isbf);
        vals[i] = v; ss += v * v;
        xrow[tid + 256 * i] = v;
    }
    __shared__ float red[256];
    red[tid] = ss; __syncthreads();
    for (int s = 128; s > 0; s >>= 1) {
        if (tid < s) red[tid] += red[tid + s];
        __syncthreads();
    }
    const float scale = 1.0f / sqrtf(red[0] / (float)DD + 1e-6f);
    float* hrow = h + (size_t)m * DD;
    for (int i = 0; i < 8; ++i)
        hrow[tid + 256 * i] = vals[i] * scale * ldf(w, tid + 256 * i, isbf);
}

// ---------------- f32 GEMM (score path): C = A @ W^T ----------------
__global__ __launch_bounds__(256, 2) void gemm_f32_k(
    const float* __restrict__ A, const void* __restrict__ Wv,
    float* __restrict__ C, int N, int K, const int* __restrict__ flag)
{
    const int isbf = *flag;
    __shared__ __align__(16) float As[16][68];
    __shared__ __align__(16) float Ws[16][68];
    const int tid = threadIdx.x;
    const int tx = tid & 15, ty = tid >> 4;
    const int bn = blockIdx.x << 6, bm = blockIdx.y << 6;
    const int lr = tid >> 2;
    const int lk = (tid & 3) << 2;
    const float* Ald = A + (size_t)(bm + lr) * K + lk;
    const size_t wbase = (size_t)(bn + lr) * K + lk;

    float acc[4][4] = {};
    for (int kt = 0; kt < K; kt += 16) {
        float4 av = *(const float4*)(Ald + kt);
        float w0, w1, w2, w3;
        if (isbf) {
            ushort4 wv = *(const ushort4*)((const unsigned short*)Wv + wbase + kt);
            w0 = us2f(wv.x); w1 = us2f(wv.y); w2 = us2f(wv.z); w3 = us2f(wv.w);
        } else {
            float4 wv = *(const float4*)((const float*)Wv + wbase + kt);
            w0 = wv.x; w1 = wv.y; w2 = wv.z; w3 = wv.w;
        }
        __syncthreads();
        As[lk + 0][lr] = av.x; As[lk + 1][lr] = av.y;
        As[lk + 2][lr] = av.z; As[lk + 3][lr] = av.w;
        Ws[lk + 0][lr] = w0; Ws[lk + 1][lr] = w1;
        Ws[lk + 2][lr] = w2; Ws[lk + 3][lr] = w3;
        __syncthreads();
#pragma unroll
        for (int kk = 0; kk < 16; ++kk) {
            float4 a4 = *(const float4*)&As[kk][ty << 2];
            float4 w4 = *(const float4*)&Ws[kk][tx << 2];
            float a_[4] = {a4.x, a4.y, a4.z, a4.w};
            float w_[4] = {w4.x, w4.y, w4.z, w4.w};
#pragma unroll
            for (int i = 0; i < 4; ++i)
#pragma unroll
                for (int j = 0; j < 4; ++j)
                    acc[i][j] = fmaf(a_[i], w_[j], acc[i][j]);
        }
    }
    const int r0 = bm + (ty << 2), c0 = bn + (tx << 2);
#pragma unroll
    for (int i = 0; i < 4; ++i) {
        float4 v = {acc[i][0], acc[i][1], acc[i][2], acc[i][3]};
        *(float4*)&C[(size_t)(r0 + i) * N + c0] = v;
    }
}

// ---------------- bf16 MFMA GEMM: C(M,N) = A(M,K) @ W(N,K)^T ----------------
// A bf16 row-major; W = input weights (f32 or bf16 per flag), converted in staging.
// 128x128 tile, BK=32, 256 thr = 4 waves (2x2), each wave 64x64 via 4x4 MFMAs.
// LDS row stride 40 bf16 (80B): 2-way bank aliasing only (free).
// EPI 0: f32 C = acc;  EPI 1: f32 C = R + acc (R may alias C);
// EPI 3: bf16 C = bf16(silu(R) * acc).
template <int EPI>
__global__ __launch_bounds__(256) void gemm_mfma_k(
    const unsigned short* __restrict__ A, const void* __restrict__ Wv,
    const float* __restrict__ R, void* __restrict__ outp,
    int N, int K, const int* __restrict__ flag)
{
    const int isbf = *flag;
    __shared__ unsigned short As[128 * 40];
    __shared__ unsigned short Ws[128 * 40];
    const int tid = threadIdx.x;
    const int lane = tid & 63;
    const int wave = tid >> 6;
    const int wm = (wave >> 1) << 6, wn = (wave & 1) << 6;
    const int bm = blockIdx.y << 7, bn = blockIdx.x << 7;
    const int srow = tid >> 1, scol = (tid & 1) << 4;
    const unsigned short* Ald = A + (size_t)(bm + srow) * K + scol;
    const size_t wldbase = (size_t)(bn + srow) * K + scol;
    unsigned short* Adst = &As[srow * 40 + scol];
    unsigned short* Wdst = &Ws[srow * 40 + scol];
    const int frow = lane & 15;
    const int fk = (lane >> 4) << 3;    // 0,8,16,24

    f32x4 acc[4][4] = {};

    for (int kt = 0; kt < K; kt += 32) {
        ushort8v a0 = *(const ushort8v*)(Ald + kt);
        ushort8v a1 = *(const ushort8v*)(Ald + kt + 8);
        ushort8v w0, w1;
        if (isbf) {
            const unsigned short* Wp = (const unsigned short*)Wv + wldbase + kt;
            w0 = *(const ushort8v*)(Wp);
            w1 = *(const ushort8v*)(Wp + 8);
        } else {
            const float* Wp = (const float*)Wv + wldbase + kt;
            float4 f0 = *(const float4*)(Wp);
            float4 f1 = *(const float4*)(Wp + 4);
            float4 f2 = *(const float4*)(Wp + 8);
            float4 f3 = *(const float4*)(Wp + 12);
            unsigned short wt[16];
            wt[0] = f2bf(f0.x); wt[1] = f2bf(f0.y); wt[2]  = f2bf(f0.z); wt[3]  = f2bf(f0.w);
            wt[4] = f2bf(f1.x); wt[5] = f2bf(f1.y); wt[6]  = f2bf(f1.z); wt[7]  = f2bf(f1.w);
            wt[8] = f2bf(f2.x); wt[9] = f2bf(f2.y); wt[10] = f2bf(f2.z); wt[11] = f2bf(f2.w);
            wt[12] = f2bf(f3.x); wt[13] = f2bf(f3.y); wt[14] = f2bf(f3.z); wt[15] = f2bf(f3.w);
            w0 = *(const ushort8v*)&wt[0];
            w1 = *(const ushort8v*)&wt[8];
        }
        __syncthreads();
        *(ushort8v*)Adst = a0;
        *(ushort8v*)(Adst + 8) = a1;
        *(ushort8v*)Wdst = w0;
        *(ushort8v*)(Wdst + 8) = w1;
        __syncthreads();

        short8 af[4], bfr[4];
#pragma unroll
        for (int i = 0; i < 4; ++i)
            af[i] = *(const short8*)&As[(wm + i * 16 + frow) * 40 + fk];
#pragma unroll
        for (int j = 0; j < 4; ++j)
            bfr[j] = *(const short8*)&Ws[(wn + j * 16 + frow) * 40 + fk];
#pragma unroll
        for (int i = 0; i < 4; ++i)
#pragma unroll
            for (int j = 0; j < 4; ++j)
                acc[i][j] = __builtin_amdgcn_mfma_f32_16x16x32_bf16(
                    af[i], bfr[j], acc[i][j], 0, 0, 0);
    }

    // C/D layout (verified m89/m91): col = lane&15, row = (lane>>4)*4 + reg
#pragma unroll
    for (int i = 0; i < 4; ++i) {
        const int r0 = bm + wm + i * 16 + ((lane >> 4) << 2);
#pragma unroll
        for (int j = 0; j < 4; ++j) {
            const int c = bn + wn + j * 16 + (lane & 15);
#pragma unroll
            for (int g = 0; g < 4; ++g) {
                const size_t idx = (size_t)(r0 + g) * N + c;
                const float v = acc[i][j][g];
                if (EPI == 0) {
                    ((float*)outp)[idx] = v;
                } else if (EPI == 1) {
                    ((float*)outp)[idx] = v + R[idx];
                } else {  // EPI == 3: silu(R) * acc -> bf16
                    const float gv = R[idx];
                    const float sg = 1.0f / (1.0f + __expf(-gv));
                    ((unsigned short*)outp)[idx] = f2bf(gv * sg * v);
                }
            }
        }
    }
}

// ---------------- RoPE (interleaved pairs), in-place on q and k_pe ----------------
__global__ __launch_bounds__(256) void rope_k(
    float* __restrict__ qb, float* __restrict__ kva,
    const void* __restrict__ fc, const void* __restrict__ fs,
    const int* __restrict__ flag)
{
    const int isbf = *flag;
    const int t = blockIdx.x;
    const int tid = threadIdx.x;
    __shared__ float c[32], s[32];
    if (tid < 32) {
        c[tid] = ldf(fc, t * 32 + tid, isbf);
        s[tid] = ldf(fs, t * 32 + tid, isbf);
    }
    __syncthreads();
    for (int p = tid; p < 512; p += 256) {
        const int h = p >> 5, i = p & 31;
        float* base = qb + (size_t)t * 3072 + h * 192 + 128 + 2 * i;
        const float x0 = base[0], x1 = base[1];
        base[0] = x0 * c[i] - x1 * s[i];
        base[1] = x0 * s[i] + x1 * c[i];
    }
    if (tid < 32) {
        float* base = kva + (size_t)t * 576 + 512 + 2 * tid;
        const float x0 = base[0], x1 = base[1];
        base[0] = x0 * c[tid] - x1 * s[tid];
        base[1] = x0 * s[tid] + x1 * c[tid];
    }
}

// ---------------- causal attention, Q-tile=8, one block per (s-tile, head) ----------------
// f32 score path; output written as bf16 (feeds the wo MFMA GEMM).
__global__ __launch_bounds__(256) void attn_k(
    const float* __restrict__ q, const float* __restrict__ kv,
    const float* __restrict__ kva, unsigned short* __restrict__ y)
{
    const int s0 = blockIdx.x * QT, h = blockIdx.y;
    const int tid = threadIdx.x;
    __shared__ __align__(16) float qv[QT][192];
    __shared__ float p[QT][TT];
    __shared__ float red[QT][32];
    __shared__ float inv[QT];

    for (int i = tid; i < QT * 192; i += 256) {
        const int r = i / 192, cpos = i % 192;
        qv[r][cpos] = q[(size_t)(s0 + r) * 3072 + h * 192 + cpos];
    }
    __syncthreads();

    const int smax = s0 + QT - 1;
    // QK: each thread computes one t-column for all 8 q-rows
    for (int t = tid; t <= smax; t += 256) {
        const float4* k4 = (const float4*)(kv + (size_t)t * 4096 + h * 256);
        const float4* pe4 = (const float4*)(kva + (size_t)t * 576 + 512);
        float d[QT] = {};
        for (int kk = 0; kk < 32; ++kk) {
            const float4 kkv = k4[kk];
#pragma unroll
            for (int r = 0; r < QT; ++r) {
                const float4 qq = *(const float4*)&qv[r][kk * 4];
                d[r] += qq.x * kkv.x + qq.y * kkv.y + qq.z * kkv.z + qq.w * kkv.w;
            }
        }
        for (int kk = 0; kk < 16; ++kk) {
            const float4 kkv = pe4[kk];
#pragma unroll
            for (int r = 0; r < QT; ++r) {
                const float4 qq = *(const float4*)&qv[r][128 + kk * 4];
                d[r] += qq.x * kkv.x + qq.y * kkv.y + qq.z * kkv.z + qq.w * kkv.w;
            }
        }
#pragma unroll
        for (int r = 0; r < QT; ++r)
            p[r][t] = (t <= s0 + r) ? d[r] * -96.0f : -1e30f;   // SOFTSCALE
    }
    __syncthreads();

    // softmax: 32 threads per row
    {
        const int r = tid >> 5, l = tid & 31;
        float mx = -1e30f;
        for (int t = l; t <= s0 + r; t += 32) mx = fmaxf(mx, p[r][t]);
        red[r][l] = mx; __syncthreads();
        if (l == 0) {
            float m2 = -1e30f;
            for (int i = 0; i < 32; ++i) m2 = fmaxf(m2, red[r][i]);
            inv[r] = m2;          // stash row max temporarily
        }
        __syncthreads();
        const float m = inv[r];
        float sum = 0.f;
        for (int t = l; t <= smax; t += 32) {
            const float e = __expf(p[r][t] - m);
            p[r][t] = e; sum += e;
        }
        __syncthreads();          // all p writes done before sum finalize/PV
        red[r][l] = sum; __syncthreads();
        if (l == 0) {
            float s2 = 0.f;
            for (int i = 0; i < 32; ++i) s2 += red[r][i];
            inv[r] = 1.0f / s2;
        }
        __syncthreads();
    }

    // PV: thread = (dim d, row-half rh); 4 independent accumulators
    {
        const int d = tid & 127, rh = (tid >> 7) << 2;
        float a0 = 0.f, a1 = 0.f, a2 = 0.f, a3 = 0.f;
        const float* vb = kv + h * 256 + 128 + d;
#pragma unroll 4
        for (int t = 0; t <= smax; ++t) {
            const float v = vb[(size_t)t * 4096];
            a0 += p[rh + 0][t] * v;
            a1 += p[rh + 1][t] * v;
            a2 += p[rh + 2][t] * v;
            a3 += p[rh + 3][t] * v;
        }
        unsigned short* yo = y + (size_t)(s0 + rh) * 2048 + h * 128 + d;
        yo[0 * 2048] = f2bf(a0 * inv[rh + 0]);
        yo[1 * 2048] = f2bf(a1 * inv[rh + 1]);
        yo[2 * 2048] = f2bf(a2 * inv[rh + 2]);
        yo[3 * 2048] = f2bf(a3 * inv[rh + 3]);
    }
}

extern "C" void kernel_launch(void* const* d_in, const int* in_sizes, int n_in,
                              void* d_out, int out_size, void* d_ws, size_t ws_size,
                              hipStream_t stream) {
    (void)in_sizes; (void)n_in; (void)out_size; (void)ws_size;
    const void* x       = d_in[0];
    const void* fcos    = d_in[2];
    const void* fsin    = d_in[3];
    const void* attn_nw = d_in[4];
    const void* wq_a    = d_in[5];
    const void* q_nw    = d_in[6];
    const void* wq_b    = d_in[7];
    const void* wkv_a   = d_in[8];
    const void* kv_nw   = d_in[9];
    const void* wkv_b   = d_in[10];
    const void* wo      = d_in[11];
    const void* ffn_nw  = d_in[12];
    const void* w1      = d_in[13];
    const void* w2      = d_in[14];
    const void* w3      = d_in[15];

    int* flag = (int*)d_ws;
    float* a  = (float*)d_ws + 64;
    const size_t M1 = 1048576;
    // Per-batch arena (float units). Peak = 14M floats + 256 B = 56.0 MiB.
    float* xf  = a;                              // [0,2M)  residual; becomes x2 in place
    float* h   = a + 2 * M1;                     // [2M,4M) f32 h (attn path)
    unsigned short* hb = (unsigned short*)(a + 2 * M1);   // [2M,3M) bf16 h2 (FFN; h dead)
    float* qa  = a + 4 * M1;                     // [4M,5.5M) dead after qb GEMM
    unsigned short* yb = (unsigned short*)(a + 4 * M1);   // [4M,5M) bf16 attn out (qa dead)
    float* qb  = a + 5 * M1 + 524288;            // [5.5M,8.5M)
    float* kva = a + 8 * M1 + 524288;            // [8.5M, +576K)
    float* kvn = kva + 589824;
    float* kvb = kvn + 524288;                   // ends at 13.5625M
    float* gb  = a + 4 * M1;                     // [4M,12M) f32 w1-out (attn bufs dead)
    unsigned short* gb2 = (unsigned short*)(a + 12 * M1); // [12M,14M) bf16 swiglu out
    float* x2  = xf;

    detect_k<<<1, 64, 0, stream>>>(x, flag);

    for (int b = 0; b < 2; ++b) {
        const size_t eoff = (size_t)b * TT * DD;
        float* outb = (float*)d_out + eoff;

        // --- attention path (f32 score chain) ---
        rmsnorm_x_k<<<TT, 256, 0, stream>>>(x, eoff, attn_nw, h, xf, flag);
        gemm_f32_k<<<dim3(1536 / 64, TT / 64), 256, 0, stream>>>(h, wq_a, qa, 1536, 2048, flag);
        rmsnorm_k<<<TT, 256, 0, stream>>>(qa, q_nw, qa, 1536, 1536, 1536, flag);
        gemm_f32_k<<<dim3(3072 / 64, TT / 64), 256, 0, stream>>>(qa, wq_b, qb, 3072, 1536, flag);
        gemm_f32_k<<<dim3(576 / 64, TT / 64), 256, 0, stream>>>(h, wkv_a, kva, 576, 2048, flag);
        rmsnorm_k<<<TT, 256, 0, stream>>>(kva, kv_nw, kvn, 512, 576, 512, flag);
        rope_k<<<TT, 256, 0, stream>>>(qb, kva, fcos, fsin, flag);
        gemm_f32_k<<<dim3(4096 / 64, TT / 64), 256, 0, stream>>>(kvn, wkv_b, kvb, 4096, 512, flag);
        attn_k<<<dim3(TT / QT, 16), 256, 0, stream>>>(qb, kvb, kva, yb);

        // --- MFMA bf16 GEMMs ---
        // x2 = xf + yb @ wo^T   (N=2048, K=2048)
        gemm_mfma_k<1><<<dim3(2048 / 128, TT / 128), 256, 0, stream>>>(
            yb, wo, xf, x2, 2048, 2048, flag);
        // hb = bf16(rmsnorm(x2))
        rmsnorm_bf_k<<<TT, 256, 0, stream>>>(x2, ffn_nw, hb, 2048, flag);
        // gb = hb @ w1^T   (N=8192, K=2048)
        gemm_mfma_k<0><<<dim3(8192 / 128, TT / 128), 256, 0, stream>>>(
            hb, w1, nullptr, gb, 8192, 2048, flag);
        // gb2 = bf16(silu(gb) * (hb @ w3^T))
        gemm_mfma_k<3><<<dim3(8192 / 128, TT / 128), 256, 0, stream>>>(
            hb, w3, gb, gb2, 8192, 2048, flag);
        // outb = x2 + gb2 @ w2^T   (N=2048, K=8192)
        gemm_mfma_k<1><<<dim3(2048 / 128, TT / 128), 256, 0, stream>>>(
            gb2, w2, x2, outb, 2048, 8192, flag);
    }
}